// Round 1
// baseline (447.374 us; speedup 1.0000x reference)
//
#include <hip/hip_runtime.h>

#define NSEQ 1024
#define BATCH 8
#define DIMC 768
#define NH 12
#define HD 64
#define SEG 6291456      // N*B*DIM elements per activation tensor
#define WSEG 589824      // DIM*DIM elements per weight

typedef __attribute__((ext_vector_type(4))) float f32x4;
typedef __attribute__((ext_vector_type(8))) short s16x8;
typedef __attribute__((ext_vector_type(8))) __bf16 bf16x8;

// async global->LDS, 16B per lane. LDS dest must be linear lane-order.
#define GLL16(gsrc, ldst) __builtin_amdgcn_global_load_lds( \
    (const __attribute__((address_space(1))) unsigned int*)(const void*)(gsrc), \
    (__attribute__((address_space(3))) unsigned int*)(void*)(ldst), 16, 0, 0)

__device__ __forceinline__ short f2bf(float f) {
  union { float f; unsigned u; } v; v.f = f;
  unsigned r = (v.u + 0x7FFFu + ((v.u >> 16) & 1u)) >> 16;
  return (short)r;
}

__device__ __forceinline__ f32x4 mfma16(bf16x8 a, bf16x8 b, f32x4 c) {
  return __builtin_amdgcn_mfma_f32_16x16x32_bf16(a, b, c, 0, 0, 0);
}

// ---------------- fp32 -> bf16 convert (4 tensors per launch) ----------------
__global__ __launch_bounds__(256) void k_cvt4(
    const float* __restrict__ a0, const float* __restrict__ a1,
    const float* __restrict__ a2, const float* __restrict__ a3,
    short* __restrict__ b0, short* __restrict__ b1,
    short* __restrict__ b2, short* __restrict__ b3, int n4) {
  const float* src; short* dst;
  switch (blockIdx.y) {
    case 0: src = a0; dst = b0; break;
    case 1: src = a1; dst = b1; break;
    case 2: src = a2; dst = b2; break;
    default: src = a3; dst = b3; break;
  }
  int i = blockIdx.x * 256 + threadIdx.x;
  if (i >= n4) return;
  float4 f = reinterpret_cast<const float4*>(src)[i];
  short4 o;
  o.x = f2bf(f.x); o.y = f2bf(f.y); o.z = f2bf(f.z); o.w = f2bf(f.w);
  reinterpret_cast<short4*>(dst)[i] = o;
}

// ---------------- input projections: Y[b,h,n,d] = X([n,b,c]) @ W^T ----------------
__global__ __launch_bounds__(256) void k_proj(
    const short* __restrict__ x0, const short* __restrict__ x1,
    const short* __restrict__ x2, const short* __restrict__ x3,
    const short* __restrict__ w0, const short* __restrict__ w1,
    const short* __restrict__ w2, const short* __restrict__ w3,
    short* __restrict__ y0, short* __restrict__ y1,
    short* __restrict__ y2, short* __restrict__ y3) {
  __shared__ __align__(16) short As[128 * 64];
  __shared__ __align__(16) short Bs[128 * 64];
  const int tid = threadIdx.x;
  const int lane = tid & 63;
  const int w = tid >> 6;
  const int wm = w >> 1, wn = w & 1;
  const int mt = blockIdx.x, nt = blockIdx.y, s = blockIdx.z;
  const short *X, *W; short* Y;
  if (s == 0)      { X = x0; W = w0; Y = y0; }
  else if (s == 1) { X = x1; W = w1; Y = y1; }
  else if (s == 2) { X = x2; W = w2; Y = y2; }
  else             { X = x3; W = w3; Y = y3; }

  f32x4 acc[4][4];
#pragma unroll
  for (int mi = 0; mi < 4; ++mi)
#pragma unroll
    for (int ni = 0; ni < 4; ++ni) acc[mi][ni] = (f32x4){0.f, 0.f, 0.f, 0.f};

  for (int kt = 0; kt < 12; ++kt) {
    __syncthreads();
#pragma unroll
    for (int ii = 0; ii < 4; ++ii) {
      int g = ii * 256 + tid;
      int o = g * 16;                       // LDS byte offset (linear lane order)
      int r = o >> 7;                       // tile row, 128B rows
      int c0 = ((o & 127) ^ ((r & 7) << 4)) >> 1;  // pre-inverse-swizzled source col
      int m = mt * 128 + r;
      const short* srcA = X + ((size_t)((m & 1023) * BATCH + (m >> 10))) * DIMC + kt * 64 + c0;
      GLL16(srcA, (char*)As + o);
      const short* srcB = W + (size_t)(nt * 128 + r) * DIMC + kt * 64 + c0;
      GLL16(srcB, (char*)Bs + o);
    }
    __syncthreads();
#pragma unroll
    for (int kk = 0; kk < 2; ++kk) {
      bf16x8 a[4], b[4];
      int ce = kk * 32 + (lane >> 4) * 8;
#pragma unroll
      for (int mi = 0; mi < 4; ++mi) {
        int ra = wm * 64 + mi * 16 + (lane & 15);
        int byte = ((ra << 7) + (ce << 1)) ^ ((ra & 7) << 4);
        a[mi] = *(const bf16x8*)((const char*)As + byte);
      }
#pragma unroll
      for (int ni = 0; ni < 4; ++ni) {
        int rb = wn * 64 + ni * 16 + (lane & 15);
        int byte = ((rb << 7) + (ce << 1)) ^ ((rb & 7) << 4);
        b[ni] = *(const bf16x8*)((const char*)Bs + byte);
      }
#pragma unroll
      for (int mi = 0; mi < 4; ++mi)
#pragma unroll
        for (int ni = 0; ni < 4; ++ni)
          acc[mi][ni] = mfma16(a[mi], b[ni], acc[mi][ni]);
    }
  }
#pragma unroll
  for (int mi = 0; mi < 4; ++mi)
#pragma unroll
    for (int ni = 0; ni < 4; ++ni)
#pragma unroll
      for (int j = 0; j < 4; ++j) {
        int m = mt * 128 + wm * 64 + mi * 16 + (lane >> 4) * 4 + j;
        int dc = nt * 128 + wn * 64 + ni * 16 + (lane & 15);
        int b_ = m >> 10, n_ = m & 1023;
        int h_ = dc >> 6, d_ = dc & 63;
        Y[((size_t)(b_ * NH + h_) * NSEQ + n_) * HD + d_] = f2bf(acc[mi][ni][j]);
      }
}

// ---------------- flash attention with shared softmax, two value streams ----------------
__global__ __launch_bounds__(256) void k_attn(
    const short* __restrict__ qh, const short* __restrict__ kh,
    const short* __restrict__ vh, const short* __restrict__ vih,
    short* __restrict__ xo, short* __restrict__ xio) {
  __shared__ __align__(16) short Ks[64 * 64];      // swizzled linear
  __shared__ __align__(16) short Vt[64][72];       // transposed, padded
  __shared__ __align__(16) short Vit[64][72];
  __shared__ __align__(16) short Pl[4][32][72];    // per-wave P staging

  const int tid = threadIdx.x;
  const int lane = tid & 63;
  const int w = tid >> 6;
  const int qt = blockIdx.x;
  const int h = blockIdx.y;
  const int b = blockIdx.z;
  const int bh = b * NH + h;
  const float CF = 0.125f * 1.44269504f;   // scale * log2(e)

  const short* qbase = qh + ((size_t)bh * NSEQ + qt * 128 + w * 32) * HD;
  bf16x8 qf[2][2];
#pragma unroll
  for (int mi = 0; mi < 2; ++mi)
#pragma unroll
    for (int kq = 0; kq < 2; ++kq)
      qf[mi][kq] = *(const bf16x8*)(qbase + (mi * 16 + (lane & 15)) * HD + kq * 32 + (lane >> 4) * 8);

  f32x4 o_[2][4], oi_[2][4];
  float m_run[2][4], l_run[2][4];
#pragma unroll
  for (int mi = 0; mi < 2; ++mi)
#pragma unroll
    for (int x = 0; x < 4; ++x) {
      o_[mi][x] = (f32x4){0.f, 0.f, 0.f, 0.f};
      oi_[mi][x] = (f32x4){0.f, 0.f, 0.f, 0.f};
      m_run[mi][x] = -__builtin_inff();
      l_run[mi][x] = 0.f;
    }

  const short* khb = kh + (size_t)bh * NSEQ * HD;
  const short* vhb = vh + (size_t)bh * NSEQ * HD;
  const short* vihb = vih + (size_t)bh * NSEQ * HD;

  for (int kt = 0; kt < 16; ++kt) {
    __syncthreads();
    // stage K (swizzled global_load_lds)
#pragma unroll
    for (int ii = 0; ii < 2; ++ii) {
      int g = ii * 256 + tid;
      int o = g * 16;
      int r = o >> 7;
      int c0 = ((o & 127) ^ ((r & 7) << 4)) >> 1;
      GLL16(khb + (size_t)(kt * 64 + r) * HD + c0, (char*)Ks + o);
    }
    // stage V / V_img transposed into padded LDS
    {
      int k_ = tid >> 2;
      int d0 = (tid & 3) * 16;
      const short* vs = vhb + (size_t)(kt * 64 + k_) * HD + d0;
      s16x8 v0 = *(const s16x8*)vs;
      s16x8 v1 = *(const s16x8*)(vs + 8);
#pragma unroll
      for (int j = 0; j < 8; ++j) Vt[d0 + j][k_] = v0[j];
#pragma unroll
      for (int j = 0; j < 8; ++j) Vt[d0 + 8 + j][k_] = v1[j];
      const short* vis = vihb + (size_t)(kt * 64 + k_) * HD + d0;
      s16x8 u0 = *(const s16x8*)vis;
      s16x8 u1 = *(const s16x8*)(vis + 8);
#pragma unroll
      for (int j = 0; j < 8; ++j) Vit[d0 + j][k_] = u0[j];
#pragma unroll
      for (int j = 0; j < 8; ++j) Vit[d0 + 8 + j][k_] = u1[j];
    }
    __syncthreads();

    // S = Q K^T for this tile
    f32x4 s_[2][4];
#pragma unroll
    for (int mi = 0; mi < 2; ++mi)
#pragma unroll
      for (int ni = 0; ni < 4; ++ni) s_[mi][ni] = (f32x4){0.f, 0.f, 0.f, 0.f};
#pragma unroll
    for (int kk = 0; kk < 2; ++kk) {
      bf16x8 kf[4];
      int ce = kk * 32 + (lane >> 4) * 8;
#pragma unroll
      for (int ni = 0; ni < 4; ++ni) {
        int rb = ni * 16 + (lane & 15);
        int byte = ((rb << 7) + (ce << 1)) ^ ((rb & 7) << 4);
        kf[ni] = *(const bf16x8*)((const char*)Ks + byte);
      }
#pragma unroll
      for (int mi = 0; mi < 2; ++mi)
#pragma unroll
        for (int ni = 0; ni < 4; ++ni)
          s_[mi][ni] = mfma16(qf[mi][kk], kf[ni], s_[mi][ni]);
    }

    // online softmax (rows: mi*16 + (lane>>4)*4 + j, shared by both streams)
    float al[2][4], rs[2][4];
#pragma unroll
    for (int mi = 0; mi < 2; ++mi)
#pragma unroll
      for (int j = 0; j < 4; ++j) {
        float v = fmaxf(fmaxf(s_[mi][0][j], s_[mi][1][j]), fmaxf(s_[mi][2][j], s_[mi][3][j]));
#pragma unroll
        for (int off = 1; off < 16; off <<= 1) v = fmaxf(v, __shfl_xor(v, off));
        float mt_ = v * CF;
        float mn = fmaxf(m_run[mi][j], mt_);
        al[mi][j] = exp2f(m_run[mi][j] - mn);
        m_run[mi][j] = mn;
        rs[mi][j] = 0.f;
      }
#pragma unroll
    for (int mi = 0; mi < 2; ++mi)
#pragma unroll
      for (int ni = 0; ni < 4; ++ni)
#pragma unroll
        for (int j = 0; j < 4; ++j) {
          float p = exp2f(s_[mi][ni][j] * CF - m_run[mi][j]);
          rs[mi][j] += p;
          Pl[w][mi * 16 + (lane >> 4) * 4 + j][ni * 16 + (lane & 15)] = f2bf(p);
        }
#pragma unroll
    for (int mi = 0; mi < 2; ++mi)
#pragma unroll
      for (int j = 0; j < 4; ++j) {
        float v = rs[mi][j];
#pragma unroll
        for (int off = 1; off < 16; off <<= 1) v += __shfl_xor(v, off);
        l_run[mi][j] = l_run[mi][j] * al[mi][j] + v;
      }
#pragma unroll
    for (int mi = 0; mi < 2; ++mi)
#pragma unroll
      for (int nd = 0; nd < 4; ++nd)
#pragma unroll
        for (int j = 0; j < 4; ++j) {
          o_[mi][nd][j] *= al[mi][j];
          oi_[mi][nd][j] *= al[mi][j];
        }

    __syncthreads();  // make cross-lane Pl writes visible before A-frag reads

    // O += P V ; O_img += P V_img
#pragma unroll
    for (int kk = 0; kk < 2; ++kk) {
      int co = kk * 32 + (lane >> 4) * 8;
      bf16x8 pa[2];
#pragma unroll
      for (int mi = 0; mi < 2; ++mi)
        pa[mi] = *(const bf16x8*)&Pl[w][mi * 16 + (lane & 15)][co];
#pragma unroll
      for (int nd = 0; nd < 4; ++nd) {
        bf16x8 vbf = *(const bf16x8*)&Vt[nd * 16 + (lane & 15)][co];
        bf16x8 vibf = *(const bf16x8*)&Vit[nd * 16 + (lane & 15)][co];
#pragma unroll
        for (int mi = 0; mi < 2; ++mi) {
          o_[mi][nd] = mfma16(pa[mi], vbf, o_[mi][nd]);
          oi_[mi][nd] = mfma16(pa[mi], vibf, oi_[mi][nd]);
        }
      }
    }
  }

  // epilogue: divide by l, write merged [b, n, h*64+d] bf16
#pragma unroll
  for (int mi = 0; mi < 2; ++mi)
#pragma unroll
    for (int j = 0; j < 4; ++j) {
      float inv = 1.0f / l_run[mi][j];
      int n_ = qt * 128 + w * 32 + mi * 16 + (lane >> 4) * 4 + j;
#pragma unroll
      for (int nd = 0; nd < 4; ++nd) {
        int dc = h * HD + nd * 16 + (lane & 15);
        size_t idx = ((size_t)b * NSEQ + n_) * DIMC + dc;
        xo[idx] = f2bf(o_[mi][nd][j] * inv);
        xio[idx] = f2bf(oi_[mi][nd][j] * inv);
      }
    }
}

// ---------------- output projections: out = X @ W^T + bias (fp32 out) ----------------
__global__ __launch_bounds__(256) void k_outproj(
    const short* __restrict__ xa, const short* __restrict__ xb,
    const short* __restrict__ wa, const short* __restrict__ wb,
    const float* __restrict__ ba, const float* __restrict__ bb,
    float* __restrict__ out) {
  __shared__ __align__(16) short As[128 * 64];
  __shared__ __align__(16) short Bs[128 * 64];
  const int tid = threadIdx.x;
  const int lane = tid & 63;
  const int w = tid >> 6;
  const int wm = w >> 1, wn = w & 1;
  const int mt = blockIdx.x, nt = blockIdx.y, s = blockIdx.z;
  const short* X = (s == 0) ? xa : xb;
  const short* W = (s == 0) ? wa : wb;
  const float* bias = (s == 0) ? ba : bb;
  float* O = out + (size_t)s * SEG;

  f32x4 acc[4][4];
#pragma unroll
  for (int mi = 0; mi < 4; ++mi)
#pragma unroll
    for (int ni = 0; ni < 4; ++ni) acc[mi][ni] = (f32x4){0.f, 0.f, 0.f, 0.f};

  for (int kt = 0; kt < 12; ++kt) {
    __syncthreads();
#pragma unroll
    for (int ii = 0; ii < 4; ++ii) {
      int g = ii * 256 + tid;
      int o = g * 16;
      int r = o >> 7;
      int c0 = ((o & 127) ^ ((r & 7) << 4)) >> 1;
      const short* srcA = X + (size_t)(mt * 128 + r) * DIMC + kt * 64 + c0;
      GLL16(srcA, (char*)As + o);
      const short* srcB = W + (size_t)(nt * 128 + r) * DIMC + kt * 64 + c0;
      GLL16(srcB, (char*)Bs + o);
    }
    __syncthreads();
#pragma unroll
    for (int kk = 0; kk < 2; ++kk) {
      bf16x8 a[4], b[4];
      int ce = kk * 32 + (lane >> 4) * 8;
#pragma unroll
      for (int mi = 0; mi < 4; ++mi) {
        int ra = wm * 64 + mi * 16 + (lane & 15);
        int byte = ((ra << 7) + (ce << 1)) ^ ((ra & 7) << 4);
        a[mi] = *(const bf16x8*)((const char*)As + byte);
      }
#pragma unroll
      for (int ni = 0; ni < 4; ++ni) {
        int rb = wn * 64 + ni * 16 + (lane & 15);
        int byte = ((rb << 7) + (ce << 1)) ^ ((rb & 7) << 4);
        b[ni] = *(const bf16x8*)((const char*)Bs + byte);
      }
#pragma unroll
      for (int mi = 0; mi < 4; ++mi)
#pragma unroll
        for (int ni = 0; ni < 4; ++ni)
          acc[mi][ni] = mfma16(a[mi], b[ni], acc[mi][ni]);
    }
  }
#pragma unroll
  for (int mi = 0; mi < 4; ++mi)
#pragma unroll
    for (int ni = 0; ni < 4; ++ni)
#pragma unroll
      for (int j = 0; j < 4; ++j) {
        int m = mt * 128 + wm * 64 + mi * 16 + (lane >> 4) * 4 + j;
        int dc = nt * 128 + wn * 64 + ni * 16 + (lane & 15);
        O[(size_t)m * DIMC + dc] = acc[mi][ni][j] + bias[dc];
      }
}

extern "C" void kernel_launch(void* const* d_in, const int* in_sizes, int n_in,
                              void* d_out, int out_size, void* d_ws, size_t ws_size,
                              hipStream_t stream) {
  (void)in_sizes; (void)n_in; (void)out_size; (void)ws_size;
  const float* q    = (const float*)d_in[0];
  const float* k    = (const float*)d_in[1];
  const float* v    = (const float*)d_in[2];
  const float* vimg = (const float*)d_in[3];
  const float* Wq   = (const float*)d_in[4];
  const float* Wk   = (const float*)d_in[5];
  const float* Wv   = (const float*)d_in[6];
  const float* Wvim = (const float*)d_in[7];
  const float* Wp   = (const float*)d_in[8];
  const float* bp   = (const float*)d_in[9];
  const float* Wpi  = (const float*)d_in[10];
  const float* bpi  = (const float*)d_in[11];

  short* ws = (short*)d_ws;
  // ws layout (shorts): 4 X streams | 6 weights | 4 projected heads | 2 attn outs
  short* xq  = ws;
  short* xk  = ws + (size_t)SEG;
  short* xv  = ws + (size_t)2 * SEG;
  short* xvi = ws + (size_t)3 * SEG;
  short* wqb  = ws + (size_t)4 * SEG;
  short* wkb  = wqb + WSEG;
  short* wvb  = wkb + WSEG;
  short* wvib = wvb + WSEG;
  short* wpb  = wvib + WSEG;
  short* wpib = wpb + WSEG;
  short* qh  = ws + (size_t)4 * SEG + 6 * (size_t)WSEG;
  short* kh  = qh + (size_t)SEG;
  short* vh  = kh + (size_t)SEG;
  short* vih = vh + (size_t)SEG;
  short* xo  = vih + (size_t)SEG;
  short* xio = xo + (size_t)SEG;

  // 1) convert to bf16
  k_cvt4<<<dim3(SEG / 4 / 256, 4), 256, 0, stream>>>(q, k, v, vimg, xq, xk, xv, xvi, SEG / 4);
  k_cvt4<<<dim3(WSEG / 4 / 256, 4), 256, 0, stream>>>(Wq, Wk, Wv, Wvim, wqb, wkb, wvb, wvib, WSEG / 4);
  k_cvt4<<<dim3(WSEG / 4 / 256, 2), 256, 0, stream>>>(Wp, Wpi, Wp, Wpi, wpb, wpib, wpb, wpib, WSEG / 4);

  // 2) input projections -> [b,h,n,d]
  k_proj<<<dim3(64, 6, 4), 256, 0, stream>>>(xq, xk, xv, xvi, wqb, wkb, wvb, wvib, qh, kh, vh, vih);

  // 3) shared-softmax attention, two value streams -> merged [b,n,c] bf16
  k_attn<<<dim3(8, NH, BATCH), 256, 0, stream>>>(qh, kh, vh, vih, xo, xio);

  // 4) output projections + bias -> fp32 d_out (x then x_im)
  k_outproj<<<dim3(64, 6, 2), 256, 0, stream>>>(xo, xio, wpb, wpib, bp, bpi, (float*)d_out);
}